// Round 7
// baseline (438.073 us; speedup 1.0000x reference)
//
#include <hip/hip_runtime.h>
#include <math.h>

#define NB 64
#define NQ 300
#define NP 6
#define ND 256
#define NF 512
#define NCL 396
#define NT 10

typedef float f4 __attribute__((ext_vector_type(4)));

__device__ __forceinline__ float dot4(f4 a, f4 b) {
    return a.x * b.x + a.y * b.y + a.z * b.z + a.w * b.w;
}
__device__ __forceinline__ float wred(float s) {
    #pragma unroll
    for (int o = 32; o; o >>= 1) s += __shfl_down(s, o, 64);
    return s;
}

// ---------------------------------------------------------------------------
// K1: blocks 0..63 -> per-class masked mean pool + key-padding bias
//     (block 0 also zeroes the sync flags for K2)
//     blocks 64+   -> feat global-average-pool rows (nontemporal stream).
// ---------------------------------------------------------------------------
__global__ __launch_bounds__(256) void pool_cls_kernel(
    const float* __restrict__ pred, const float* __restrict__ hs,
    const float* __restrict__ f0, const float* __restrict__ f1,
    const float* __restrict__ f2, const float* __restrict__ f3,
    float* __restrict__ pooled, float* __restrict__ tokG,
    float* __restrict__ biasW, int* __restrict__ flagW)
{
    const int bid = blockIdx.x;
    const int tid = threadIdx.x;
    __shared__ float shm[1824];

    if (bid < NB) {
        if (bid == 0) flagW[tid] = 0;   // 256 flag slots, zeroed every call
        const int b = bid;
        float* maskL = shm;
        float* countsL = shm + 1800;
        for (int i = tid; i < NQ * NP; i += 256) {
            float x = pred[(size_t)b * NQ * NP + i];
            float sg = 1.f / (1.f + expf(-x));
            maskL[i] = (sg > 0.3f) ? 1.f : 0.f;
        }
        __syncthreads();
        if (tid < NP) {
            float c = 0.f;
            for (int q = 0; q < NQ; q++) c += maskL[q * NP + tid];
            countsL[tid] = c;
        }
        __syncthreads();
        float acc[NP] = {0.f, 0.f, 0.f, 0.f, 0.f, 0.f};
        const float* hsb = hs + (size_t)b * NQ * ND + tid;
        for (int q = 0; q < NQ; q++) {
            float h = hsb[(size_t)q * ND];
            #pragma unroll
            for (int p = 0; p < NP; p++) acc[p] += maskL[q * NP + p] * h;
        }
        bool anyv = false;
        #pragma unroll
        for (int p = 0; p < NP; p++) anyv = anyv || (countsL[p] > 0.f);
        #pragma unroll
        for (int p = 0; p < NP; p++) {
            float cm = acc[p] / fmaxf(countsL[p], 1.f);
            if (p == 0 && !anyv) cm = hs[(size_t)b * NQ * ND + tid];
            tokG[(size_t)b * 1536 + p * ND + tid] = cm;
        }
        if (tid < 16) {
            float bv = 0.f;
            if (tid < NP) {
                bool v = countsL[tid] > 0.f;
                if (tid == 0 && !anyv) v = true;
                bv = v ? 0.f : -1e30f;
            }
            biasW[b * 16 + tid] = bv;
        }
        return;
    }

    const int row = bid - NB;
    const int scale = row >> 14;
    const int rr = row & 16383;
    const int b = rr >> 8;
    const int d = rr & 255;
    const float* src;
    int n;
    switch (scale) {
        case 0: src = f0; n = 96 * 96; break;
        case 1: src = f1; n = 48 * 48; break;
        case 2: src = f2; n = 24 * 24; break;
        default: src = f3; n = 12 * 12; break;
    }
    const f4* p4 = reinterpret_cast<const f4*>(src + ((size_t)b * ND + d) * (size_t)n);
    int n4 = n >> 2;
    float s = 0.f;
    for (int i = tid; i < n4; i += 256) {
        f4 v = __builtin_nontemporal_load(&p4[i]);
        s += v.x + v.y + v.z + v.w;
    }
    s = wred(s);
    int wid = tid >> 6, lane = tid & 63;
    if (lane == 0) shm[wid] = s;
    __syncthreads();
    if (tid == 0) {
        float t = shm[0] + shm[1] + shm[2] + shm[3];
        pooled[((size_t)b * 4 + scale) * ND + d] = t / (float)n;
    }
}

// ---------------------------------------------------------------------------
// helpers for the pairwise spin barrier (device-scope, G16 pattern)
// ---------------------------------------------------------------------------
__device__ __forceinline__ void pair_sync(int* flag, int tid) {
    __threadfence();          // make this thread's global writes device-visible
    __syncthreads();          // all block threads' writes ordered before signal
    if (tid == 0)
        __hip_atomic_fetch_add(flag, 1, __ATOMIC_RELEASE, __HIP_MEMORY_SCOPE_AGENT);
    while (__hip_atomic_load(flag, __ATOMIC_ACQUIRE, __HIP_MEMORY_SCOPE_AGENT) < 2)
        __builtin_amdgcn_s_sleep(8);
}

// ---------------------------------------------------------------------------
// K2: row-split fused transformer. 128 blocks (b, half) x 512 threads.
// Each block owns 5 token rows end-to-end; cross-block exchange only for
// attention K/V (per layer) and the final pooled classifier input.
// ---------------------------------------------------------------------------
__global__ __launch_bounds__(512) void xform2_kernel(
    const float* __restrict__ pooled, const float* __restrict__ tokG,
    const float* __restrict__ biasW,
    const float* __restrict__ ipw, const float* __restrict__ ipb,
    const float* __restrict__ inw, const float* __restrict__ inb,
    const float* __restrict__ ow, const float* __restrict__ ob,
    const float* __restrict__ l1w, const float* __restrict__ l1b,
    const float* __restrict__ l2w, const float* __restrict__ l2b,
    const float* __restrict__ n1w, const float* __restrict__ n1b,
    const float* __restrict__ n2w, const float* __restrict__ n2b,
    const float* __restrict__ c1w, const float* __restrict__ c1b,
    const float* __restrict__ c2w, const float* __restrict__ c2b,
    float* __restrict__ qkvW, float* __restrict__ xsW,
    int* __restrict__ flagW, float* __restrict__ out)
{
    const int b = blockIdx.x >> 1;
    const int hf = blockIdx.x & 1;
    const int r0 = hf * 5;
    const int tid = threadIdx.x;
    const int lane = tid & 63;
    const int wv = tid >> 6;

    __shared__ __align__(16) float xsL[5 * ND];    // own rows, current x
    __shared__ __align__(16) float kvL[NT * 512];  // K|V all rows; pld in prologue
    __shared__ __align__(16) float qL[5 * ND];     // own q ; ct in epilogue
    __shared__ __align__(16) float aoL[5 * ND];    // attn out / resid / cls h
    __shared__ __align__(16) float pS[2 * 5 * ND]; // K-split partials
    __shared__ __align__(16) float h1L[5 * NF];    // ff hidden
    __shared__ float sc[400];
    __shared__ float stats[16];
    __shared__ float biasK[16];

    if (tid < 16) biasK[tid] = biasW[b * 16 + tid];

    // ---------------- prologue: own 5 rows into xsL ----------------
    if (hf == 0) {
        for (int i = tid; i < 1280; i += 512) xsL[i] = tokG[(size_t)b * 1536 + i];
        __syncthreads();
    } else {
        if (tid < ND) xsL[tid] = tokG[(size_t)b * 1536 + 5 * ND + tid];  // part 5
        for (int i = tid; i < 1024; i += 512) kvL[i] = pooled[(size_t)b * 1024 + i];
        __syncthreads();
        const f4* pld4 = reinterpret_cast<const f4*>(kvL);
        for (int idx = tid; idx < 1024; idx += 512) {
            int i = idx >> 8, c = idx & 255;
            const f4* w4 = reinterpret_cast<const f4*>(ipw + ((size_t)i * ND + c) * ND);
            float acc = 0.f;
            for (int k4 = 0; k4 < 64; k4++) acc += dot4(w4[k4], pld4[i * 64 + k4]);
            xsL[(i + 1) * ND + c] = acc + ipb[i * ND + c];   // local rows 1..4
        }
        __syncthreads();
    }

    const f4* xsL4 = reinterpret_cast<const f4*>(xsL);
    const f4* aoL4 = reinterpret_cast<const f4*>(aoL);
    const f4* h1L4 = reinterpret_cast<const f4*>(h1L);

    for (int l = 0; l < 2; l++) {
        // ---- (a) QKV own rows -> global (double-buffered by l) ----
        for (int c = tid; c < 768; c += 512) {
            const f4* w4 = reinterpret_cast<const f4*>(inw + ((size_t)l * 768 + c) * ND);
            float acc[5] = {0.f, 0.f, 0.f, 0.f, 0.f};
            for (int k4 = 0; k4 < 64; k4++) {
                f4 wv4 = w4[k4];
                #pragma unroll
                for (int r = 0; r < 5; r++) acc[r] += dot4(wv4, xsL4[r * 64 + k4]);
            }
            float bb = inb[l * 768 + c];
            #pragma unroll
            for (int r = 0; r < 5; r++)
                qkvW[((size_t)(l * NB + b) * NT + r0 + r) * 768 + c] = acc[r] + bb;
        }
        pair_sync(&flagW[b * 4 + l], tid);

        // ---- stage K,V (all rows) + own q ----
        for (int i = tid; i < 5120; i += 512) {
            int r = i >> 9, c = i & 511;
            kvL[i] = qkvW[((size_t)(l * NB + b) * NT + r) * 768 + 256 + c];
        }
        for (int i = tid; i < 1280; i += 512) {
            int r = i >> 8, c = i & 255;
            qL[i] = qkvW[((size_t)(l * NB + b) * NT + r0 + r) * 768 + c];
        }
        __syncthreads();

        // ---- (b) scores (+bias) for own 5 q-rows ----
        if (tid < 400) {
            int h = tid / 50, rem = tid - 50 * h;
            int qr = rem / 10, kr = rem - 10 * qr;
            float s = 0.f;
            #pragma unroll
            for (int dh = 0; dh < 32; dh++)
                s += qL[qr * ND + h * 32 + dh] * kvL[kr * 512 + h * 32 + dh];
            sc[tid] = s * 0.17677669529663687f + biasK[kr];
        }
        __syncthreads();
        if (tid < 40) {
            float* row = &sc[tid * 10];
            float m = row[0];
            #pragma unroll
            for (int k = 1; k < 10; k++) m = fmaxf(m, row[k]);
            float ss = 0.f;
            #pragma unroll
            for (int k = 0; k < 10; k++) { float e = expf(row[k] - m); row[k] = e; ss += e; }
            float inv = 1.f / ss;
            #pragma unroll
            for (int k = 0; k < 10; k++) row[k] *= inv;
        }
        __syncthreads();

        // ---- (c) attn @ V -> aoL ----
        for (int idx = tid; idx < 1280; idx += 512) {
            int r = idx >> 8, col = idx & 255, h = col >> 5;
            float s = 0.f;
            #pragma unroll
            for (int kr = 0; kr < 10; kr++)
                s += sc[h * 50 + r * 10 + kr] * kvL[kr * 512 + 256 + col];
            aoL[idx] = s;
        }
        __syncthreads();

        // ---- (d) out_proj (2-way K-split) ----
        {
            int kh = tid >> 8, c = tid & 255;
            const f4* w4 = reinterpret_cast<const f4*>(ow + ((size_t)l * ND + c) * ND + kh * 128);
            float acc[5] = {0.f, 0.f, 0.f, 0.f, 0.f};
            for (int k4 = 0; k4 < 32; k4++) {
                f4 wv4 = w4[k4];
                #pragma unroll
                for (int r = 0; r < 5; r++) acc[r] += dot4(wv4, aoL4[r * 64 + kh * 32 + k4]);
            }
            #pragma unroll
            for (int r = 0; r < 5; r++) pS[kh * 1280 + r * ND + c] = acc[r];
        }
        __syncthreads();
        for (int idx = tid; idx < 1280; idx += 512)
            aoL[idx] = xsL[idx] + pS[idx] + pS[1280 + idx] + ob[l * ND + (idx & 255)];
        __syncthreads();

        // ---- (e) LN1 -> xsL ----
        if (wv < 5) {
            int r = wv;
            float v0 = aoL[r * ND + lane], v1 = aoL[r * ND + 64 + lane];
            float v2 = aoL[r * ND + 128 + lane], v3 = aoL[r * ND + 192 + lane];
            float s = wred(v0 + v1 + v2 + v3);
            float q = wred(v0 * v0 + v1 * v1 + v2 * v2 + v3 * v3);
            if (lane == 0) {
                float m = s * (1.f / ND);
                stats[r] = m;
                stats[8 + r] = rsqrtf(fmaxf(q * (1.f / ND) - m * m, 0.f) + 1e-5f);
            }
        }
        __syncthreads();
        for (int idx = tid; idx < 1280; idx += 512) {
            int r = idx >> 8, c = idx & 255;
            xsL[idx] = (aoL[idx] - stats[r]) * stats[8 + r] * n1w[l * ND + c] + n1b[l * ND + c];
        }
        __syncthreads();

        // ---- (f) FF1: 512 cols, one per thread ----
        {
            int c = tid;
            const f4* w4 = reinterpret_cast<const f4*>(l1w + ((size_t)l * NF + c) * ND);
            float acc[5] = {0.f, 0.f, 0.f, 0.f, 0.f};
            for (int k4 = 0; k4 < 64; k4++) {
                f4 wv4 = w4[k4];
                #pragma unroll
                for (int r = 0; r < 5; r++) acc[r] += dot4(wv4, xsL4[r * 64 + k4]);
            }
            float bb = l1b[l * NF + c];
            #pragma unroll
            for (int r = 0; r < 5; r++) h1L[r * NF + c] = fmaxf(acc[r] + bb, 0.f);
        }
        __syncthreads();

        // ---- (g) FF2 (2-way K-split) + residual ----
        {
            int kh = tid >> 8, c = tid & 255;
            const f4* w4 = reinterpret_cast<const f4*>(l2w + ((size_t)l * ND + c) * NF + kh * 256);
            float acc[5] = {0.f, 0.f, 0.f, 0.f, 0.f};
            for (int k4 = 0; k4 < 64; k4++) {
                f4 wv4 = w4[k4];
                #pragma unroll
                for (int r = 0; r < 5; r++) acc[r] += dot4(wv4, h1L4[r * 128 + kh * 64 + k4]);
            }
            #pragma unroll
            for (int r = 0; r < 5; r++) pS[kh * 1280 + r * ND + c] = acc[r];
        }
        __syncthreads();
        for (int idx = tid; idx < 1280; idx += 512)
            aoL[idx] = xsL[idx] + pS[idx] + pS[1280 + idx] + l2b[l * ND + (idx & 255)];
        __syncthreads();

        // ---- (h) LN2 -> xsL ----
        if (wv < 5) {
            int r = wv;
            float v0 = aoL[r * ND + lane], v1 = aoL[r * ND + 64 + lane];
            float v2 = aoL[r * ND + 128 + lane], v3 = aoL[r * ND + 192 + lane];
            float s = wred(v0 + v1 + v2 + v3);
            float q = wred(v0 * v0 + v1 * v1 + v2 * v2 + v3 * v3);
            if (lane == 0) {
                float m = s * (1.f / ND);
                stats[r] = m;
                stats[8 + r] = rsqrtf(fmaxf(q * (1.f / ND) - m * m, 0.f) + 1e-5f);
            }
        }
        __syncthreads();
        for (int idx = tid; idx < 1280; idx += 512) {
            int r = idx >> 8, c = idx & 255;
            xsL[idx] = (aoL[idx] - stats[r]) * stats[8 + r] * n2w[l * ND + c] + n2b[l * ND + c];
        }
        __syncthreads();
    }

    // ---------------- epilogue ----------------
    for (int idx = tid; idx < 1280; idx += 512)
        xsW[((size_t)b * NT + r0 + (idx >> 8)) * ND + (idx & 255)] = xsL[idx];
    pair_sync(&flagW[b * 4 + 2], tid);

    // masked mean pool (redundant in both halves) -> qL[0..256)
    if (tid < ND) {
        float len = 0.f, s = 0.f;
        #pragma unroll
        for (int r = 0; r < NT; r++) {
            float v = (biasK[r] == 0.f) ? 1.f : 0.f;
            len += v;
            s += v * xsW[((size_t)b * NT + r) * ND + tid];
        }
        qL[tid] = s / fmaxf(len, 1.f);
    }
    __syncthreads();

    // cls1 (redundant): 512 cols, one per thread -> aoL[0..512)
    {
        const f4* w4 = reinterpret_cast<const f4*>(c1w + (size_t)tid * ND);
        const f4* ct4 = reinterpret_cast<const f4*>(qL);
        float acc = 0.f;
        for (int k4 = 0; k4 < 64; k4++) acc += dot4(w4[k4], ct4[k4]);
        aoL[tid] = fmaxf(acc + c1b[tid], 0.f);
    }
    __syncthreads();

    // cls2: this half owns outputs [hf*198, hf*198+198), 2-way K-split
    {
        int kh = tid >> 8, o = tid & 255;
        if (o < 198) {
            int oc = hf * 198 + o;
            const f4* w4 = reinterpret_cast<const f4*>(c2w + (size_t)oc * NF + kh * 256);
            const f4* h4 = reinterpret_cast<const f4*>(aoL);
            float acc = 0.f;
            for (int k4 = 0; k4 < 64; k4++) acc += dot4(w4[k4], h4[kh * 64 + k4]);
            pS[kh * 256 + o] = acc;
        }
    }
    __syncthreads();
    if (tid < 198) {
        int oc = hf * 198 + tid;
        out[(size_t)b * NCL + oc] = pS[tid] + pS[256 + tid] + c2b[oc];
    }
}

// ---------------------------------------------------------------------------
extern "C" void kernel_launch(void* const* d_in, const int* in_sizes, int n_in,
                              void* d_out, int out_size, void* d_ws, size_t ws_size,
                              hipStream_t stream)
{
    const float* pred = (const float*)d_in[0];
    const float* hs   = (const float*)d_in[1];
    const float* f0   = (const float*)d_in[2];
    const float* f1   = (const float*)d_in[3];
    const float* f2   = (const float*)d_in[4];
    const float* f3   = (const float*)d_in[5];
    const float* ipw  = (const float*)d_in[6];
    const float* ipb  = (const float*)d_in[7];
    const float* inw  = (const float*)d_in[8];
    const float* inb  = (const float*)d_in[9];
    const float* ow   = (const float*)d_in[10];
    const float* ob   = (const float*)d_in[11];
    const float* l1w  = (const float*)d_in[12];
    const float* l1b  = (const float*)d_in[13];
    const float* l2w  = (const float*)d_in[14];
    const float* l2b  = (const float*)d_in[15];
    const float* ln1w = (const float*)d_in[16];
    const float* ln1b = (const float*)d_in[17];
    const float* ln2w = (const float*)d_in[18];
    const float* ln2b = (const float*)d_in[19];
    const float* c1w  = (const float*)d_in[20];
    const float* c1b  = (const float*)d_in[21];
    const float* c2w  = (const float*)d_in[22];
    const float* c2b  = (const float*)d_in[23];

    float* ws = (float*)d_ws;
    float* pooled = ws;                          //  65536
    float* tokG   = pooled + NB * 4 * ND;        //  98304
    float* biasW  = tokG + NB * 1536;            //   1024
    float* qkvW   = biasW + NB * 16;             // 983040 (2 layers)
    float* xsW    = qkvW + 2 * NB * NT * 768;    // 163840
    int*   flagW  = (int*)(xsW + NB * NT * ND);  //    256

    pool_cls_kernel<<<NB + 4 * NB * ND, 256, 0, stream>>>(
        pred, hs, f0, f1, f2, f3, pooled, tokG, biasW, flagW);
    xform2_kernel<<<2 * NB, 512, 0, stream>>>(
        pooled, tokG, biasW, ipw, ipb, inw, inb, ow, ob, l1w, l1b, l2w, l2b,
        ln1w, ln1b, ln2w, ln2b, c1w, c1b, c2w, c2b,
        qkvW, xsW, flagW, (float*)d_out);
}

// Round 8
// 369.119 us; speedup vs baseline: 1.1868x; 1.1868x over previous
//
#include <hip/hip_runtime.h>
#include <math.h>

#define NB 64
#define NQ 300
#define NP 6
#define ND 256
#define NF 512
#define NCL 396
#define NT 10

typedef float f4 __attribute__((ext_vector_type(4)));

__device__ __forceinline__ float dot4(f4 a, f4 b) {
    return a.x * b.x + a.y * b.y + a.z * b.z + a.w * b.w;
}
__device__ __forceinline__ float wred(float s) {
    #pragma unroll
    for (int o = 32; o; o >>= 1) s += __shfl_down(s, o, 64);
    return s;
}

// ---------------------------------------------------------------------------
// K1: blocks 0..63 -> per-class masked mean pool + key-padding bias
//     blocks 64+   -> feat global-average-pool rows (nontemporal stream).
// (unchanged from R5 — pool is at ~80% HBM peak)
// ---------------------------------------------------------------------------
__global__ __launch_bounds__(256) void pool_cls_kernel(
    const float* __restrict__ pred, const float* __restrict__ hs,
    const float* __restrict__ f0, const float* __restrict__ f1,
    const float* __restrict__ f2, const float* __restrict__ f3,
    float* __restrict__ pooled, float* __restrict__ tokG,
    float* __restrict__ biasW)
{
    const int bid = blockIdx.x;
    const int tid = threadIdx.x;
    __shared__ float shm[1824];

    if (bid < NB) {
        const int b = bid;
        float* maskL = shm;
        float* countsL = shm + 1800;
        for (int i = tid; i < NQ * NP; i += 256) {
            float x = pred[(size_t)b * NQ * NP + i];
            float sg = 1.f / (1.f + expf(-x));
            maskL[i] = (sg > 0.3f) ? 1.f : 0.f;
        }
        __syncthreads();
        if (tid < NP) {
            float c = 0.f;
            for (int q = 0; q < NQ; q++) c += maskL[q * NP + tid];
            countsL[tid] = c;
        }
        __syncthreads();
        float acc[NP] = {0.f, 0.f, 0.f, 0.f, 0.f, 0.f};
        const float* hsb = hs + (size_t)b * NQ * ND + tid;
        for (int q = 0; q < NQ; q++) {
            float h = hsb[(size_t)q * ND];
            #pragma unroll
            for (int p = 0; p < NP; p++) acc[p] += maskL[q * NP + p] * h;
        }
        bool anyv = false;
        #pragma unroll
        for (int p = 0; p < NP; p++) anyv = anyv || (countsL[p] > 0.f);
        #pragma unroll
        for (int p = 0; p < NP; p++) {
            float cm = acc[p] / fmaxf(countsL[p], 1.f);
            if (p == 0 && !anyv) cm = hs[(size_t)b * NQ * ND + tid];
            tokG[(size_t)b * 1536 + p * ND + tid] = cm;
        }
        if (tid < 16) {
            float bv = 0.f;
            if (tid < NP) {
                bool v = countsL[tid] > 0.f;
                if (tid == 0 && !anyv) v = true;
                bv = v ? 0.f : -1e30f;
            }
            biasW[b * 16 + tid] = bv;
        }
        return;
    }

    const int row = bid - NB;
    const int scale = row >> 14;
    const int rr = row & 16383;
    const int b = rr >> 8;
    const int d = rr & 255;
    const float* src;
    int n;
    switch (scale) {
        case 0: src = f0; n = 96 * 96; break;
        case 1: src = f1; n = 48 * 48; break;
        case 2: src = f2; n = 24 * 24; break;
        default: src = f3; n = 12 * 12; break;
    }
    const f4* p4 = reinterpret_cast<const f4*>(src + ((size_t)b * ND + d) * (size_t)n);
    int n4 = n >> 2;
    float s = 0.f;
    for (int i = tid; i < n4; i += 256) {
        f4 v = __builtin_nontemporal_load(&p4[i]);
        s += v.x + v.y + v.z + v.w;
    }
    s = wred(s);
    int wid = tid >> 6, lane = tid & 63;
    if (lane == 0) shm[wid] = s;
    __syncthreads();
    if (tid == 0) {
        float t = shm[0] + shm[1] + shm[2] + shm[3];
        pooled[((size_t)b * 4 + scale) * ND + d] = t / (float)n;
    }
}

// ---------------------------------------------------------------------------
// K2: fused per-batch transformer. 64 blocks x 1024 threads (4 waves/SIMD).
// Column-parallel GEMMs with K-split partials: all 16 waves active in every
// heavy phase; per-thread serial weight-load chains 16-64 (vs 64-128 in R5).
// No weight-read duplication (K-split reads disjoint weight slices).
// ---------------------------------------------------------------------------
__global__ __launch_bounds__(1024) void xform_kernel(
    const float* __restrict__ pooled, const float* __restrict__ tokG,
    const float* __restrict__ biasW,
    const float* __restrict__ ipw, const float* __restrict__ ipb,
    const float* __restrict__ inw, const float* __restrict__ inb,
    const float* __restrict__ ow, const float* __restrict__ ob,
    const float* __restrict__ l1w, const float* __restrict__ l1b,
    const float* __restrict__ l2w, const float* __restrict__ l2b,
    const float* __restrict__ n1w, const float* __restrict__ n1b,
    const float* __restrict__ n2w, const float* __restrict__ n2b,
    const float* __restrict__ c1w, const float* __restrict__ c1b,
    const float* __restrict__ c2w, const float* __restrict__ c2b,
    float* __restrict__ out)
{
    const int b = blockIdx.x;
    const int tid = threadIdx.x;
    const int lane = tid & 63;
    const int wid = tid >> 6;

    __shared__ __align__(16) float xs[NT * ND];     // 2560 current x
    __shared__ __align__(16) float qs[4 * NT * ND]; // 10240 qkv / K-split partials
    __shared__ __align__(16) float xr[NT * ND];     // 2560 attn-out / resid / ct
    __shared__ __align__(16) float h1[NT * NF];     // 5120 pld / ff hidden / cls h
    __shared__ float sc[800];
    __shared__ float stats[32];
    __shared__ float biasK[16];

    // ---------------- stage ----------------
    for (int i = tid; i < 1536; i += 1024) xs[i] = tokG[(size_t)b * 1536 + i];
    h1[tid] = pooled[(size_t)b * 1024 + tid];        // pld
    if (tid < 16) biasK[tid] = biasW[b * 16 + tid];
    __syncthreads();

    const f4* xs4 = reinterpret_cast<const f4*>(xs);
    const f4* xr4 = reinterpret_cast<const f4*>(xr);
    const f4* h14 = reinterpret_cast<const f4*>(h1);

    // ---- img tokens: 1024 outputs, 1/thread ----
    {
        const int i = tid >> 8, c = tid & 255;
        const f4* w4 = reinterpret_cast<const f4*>(ipw + ((size_t)i * ND + c) * ND);
        float acc = 0.f;
        #pragma unroll 4
        for (int k4 = 0; k4 < 64; k4++) acc += dot4(w4[k4], h14[i * 64 + k4]);
        __syncthreads();                              // pld reads done
        xs[(6 + i) * ND + c] = acc + ipb[i * ND + c];
    }
    __syncthreads();

    for (int l = 0; l < 2; l++) {
        // ---- (a) QKV: 768 cols, 1/thread (waves 12-15 idle), full K ----
        if (tid < 768) {
            const int c = tid;
            const f4* w4 = reinterpret_cast<const f4*>(inw + ((size_t)l * 768 + c) * ND);
            float acc[NT];
            #pragma unroll
            for (int r = 0; r < NT; r++) acc[r] = 0.f;
            #pragma unroll 4
            for (int k4 = 0; k4 < 64; k4++) {
                f4 wv = w4[k4];
                #pragma unroll
                for (int r = 0; r < NT; r++) acc[r] += dot4(wv, xs4[r * 64 + k4]);
            }
            float bb = inb[l * 768 + c];
            #pragma unroll
            for (int r = 0; r < NT; r++) qs[r * 768 + c] = acc[r] + bb;
        }
        __syncthreads();

        // ---- (b) scores + bias ----
        if (tid < 800) {
            int h = tid / 100, rem = tid - 100 * h;
            int qr = rem / 10, kr = rem - 10 * qr;
            const float* qp = &qs[qr * 768 + h * 32];
            const float* kp = &qs[kr * 768 + ND + h * 32];
            float s = 0.f;
            #pragma unroll
            for (int dh = 0; dh < 32; dh++) s += qp[dh] * kp[dh];
            sc[tid] = s * 0.17677669529663687f + biasK[kr];
        }
        __syncthreads();

        // ---- (c) softmax ----
        if (tid < 80) {
            float* row = &sc[tid * 10];
            float m = row[0];
            #pragma unroll
            for (int k = 1; k < 10; k++) m = fmaxf(m, row[k]);
            float ss = 0.f;
            #pragma unroll
            for (int k = 0; k < 10; k++) { float e = expf(row[k] - m); row[k] = e; ss += e; }
            float inv = 1.f / ss;
            #pragma unroll
            for (int k = 0; k < 10; k++) row[k] *= inv;
        }
        __syncthreads();

        // ---- (d) attn @ V -> xr ----
        for (int idx = tid; idx < NT * ND; idx += 1024) {
            int r = idx >> 8, col = idx & 255, h = col >> 5;
            float s = 0.f;
            #pragma unroll
            for (int kr = 0; kr < 10; kr++)
                s += sc[h * 100 + r * 10 + kr] * qs[kr * 768 + 512 + col];
            xr[idx] = s;
        }
        __syncthreads();

        // ---- (e) out_proj, K-split-4: all 1024 threads, 16 f4 each ----
        {
            const int kh = tid >> 8, c = tid & 255;
            const f4* w4 = reinterpret_cast<const f4*>(ow + ((size_t)l * ND + c) * ND + kh * 64);
            float acc[NT];
            #pragma unroll
            for (int r = 0; r < NT; r++) acc[r] = 0.f;
            #pragma unroll 4
            for (int k4 = 0; k4 < 16; k4++) {
                f4 wv = w4[k4];
                #pragma unroll
                for (int r = 0; r < NT; r++) acc[r] += dot4(wv, xr4[r * 64 + kh * 16 + k4]);
            }
            __syncthreads();             // xr reads done; qs(qkv) dead
            #pragma unroll
            for (int r = 0; r < NT; r++) qs[kh * 2560 + r * ND + c] = acc[r];
        }
        __syncthreads();
        for (int idx = tid; idx < NT * ND; idx += 1024)
            xr[idx] = xs[idx] + qs[idx] + qs[2560 + idx] + qs[5120 + idx] + qs[7680 + idx]
                    + ob[l * ND + (idx & 255)];
        __syncthreads();

        // ---- (f) LN1: xr -> xs ----
        if (wid < NT) {
            int r = wid;
            float v0 = xr[r * ND + lane], v1 = xr[r * ND + 64 + lane];
            float v2 = xr[r * ND + 128 + lane], v3 = xr[r * ND + 192 + lane];
            float s = wred(v0 + v1 + v2 + v3);
            float q = wred(v0 * v0 + v1 * v1 + v2 * v2 + v3 * v3);
            if (lane == 0) {
                float m = s * (1.f / ND);
                stats[r] = m;
                stats[16 + r] = rsqrtf(fmaxf(q * (1.f / ND) - m * m, 0.f) + 1e-5f);
            }
        }
        __syncthreads();
        for (int idx = tid; idx < NT * ND; idx += 1024) {
            int r = idx >> 8, c = idx & 255;
            xs[idx] = (xr[idx] - stats[r]) * stats[16 + r] * n1w[l * ND + c] + n1b[l * ND + c];
        }
        __syncthreads();

        // ---- (g) FF1, K-split-2: all threads, 32 f4 each ----
        {
            const int kh = tid >> 9, c = tid & 511;
            const f4* w4 = reinterpret_cast<const f4*>(l1w + ((size_t)l * NF + c) * ND + kh * 128);
            float acc[NT];
            #pragma unroll
            for (int r = 0; r < NT; r++) acc[r] = 0.f;
            #pragma unroll 4
            for (int k4 = 0; k4 < 32; k4++) {
                f4 wv = w4[k4];
                #pragma unroll
                for (int r = 0; r < NT; r++) acc[r] += dot4(wv, xs4[r * 64 + kh * 32 + k4]);
            }
            #pragma unroll
            for (int r = 0; r < NT; r++) qs[kh * 5120 + r * NF + c] = acc[r];
        }
        __syncthreads();
        for (int idx = tid; idx < NT * NF; idx += 1024)
            h1[idx] = fmaxf(qs[idx] + qs[5120 + idx] + l1b[l * NF + (idx & 511)], 0.f);
        __syncthreads();

        // ---- (h) FF2, K-split-4: all threads, 32 f4 each ----
        {
            const int kh = tid >> 8, c = tid & 255;
            const f4* w4 = reinterpret_cast<const f4*>(l2w + ((size_t)l * ND + c) * NF + kh * 128);
            float acc[NT];
            #pragma unroll
            for (int r = 0; r < NT; r++) acc[r] = 0.f;
            #pragma unroll 4
            for (int k4 = 0; k4 < 32; k4++) {
                f4 wv = w4[k4];
                #pragma unroll
                for (int r = 0; r < NT; r++) acc[r] += dot4(wv, h14[r * 128 + kh * 32 + k4]);
            }
            __syncthreads();             // h1 reads + previous qs reads done
            #pragma unroll
            for (int r = 0; r < NT; r++) qs[kh * 2560 + r * ND + c] = acc[r];
        }
        __syncthreads();
        for (int idx = tid; idx < NT * ND; idx += 1024)
            xr[idx] = xs[idx] + qs[idx] + qs[2560 + idx] + qs[5120 + idx] + qs[7680 + idx]
                    + l2b[l * ND + (idx & 255)];
        __syncthreads();

        // ---- (i) LN2: xr -> xs ----
        if (wid < NT) {
            int r = wid;
            float v0 = xr[r * ND + lane], v1 = xr[r * ND + 64 + lane];
            float v2 = xr[r * ND + 128 + lane], v3 = xr[r * ND + 192 + lane];
            float s = wred(v0 + v1 + v2 + v3);
            float q = wred(v0 * v0 + v1 * v1 + v2 * v2 + v3 * v3);
            if (lane == 0) {
                float m = s * (1.f / ND);
                stats[r] = m;
                stats[16 + r] = rsqrtf(fmaxf(q * (1.f / ND) - m * m, 0.f) + 1e-5f);
            }
        }
        __syncthreads();
        for (int idx = tid; idx < NT * ND; idx += 1024) {
            int r = idx >> 8, c = idx & 255;
            xs[idx] = (xr[idx] - stats[r]) * stats[16 + r] * n2w[l * ND + c] + n2b[l * ND + c];
        }
        __syncthreads();
    }

    // ---------------- epilogue ----------------
    // masked mean pool -> xr[0..256)
    if (tid < ND) {
        float len = 0.f, s = 0.f;
        #pragma unroll
        for (int r = 0; r < NT; r++) {
            float v = (biasK[r] == 0.f) ? 1.f : 0.f;
            len += v;
            s += v * xs[r * ND + tid];
        }
        xr[tid] = s / fmaxf(len, 1.f);
    }
    __syncthreads();

    // cls1, K-split-2: all threads, 32 f4 each -> partials, combine -> h1[0..512)
    {
        const int kh = tid >> 9, c = tid & 511;
        const f4* w4 = reinterpret_cast<const f4*>(c1w + (size_t)c * ND + kh * 128);
        float acc = 0.f;
        #pragma unroll 4
        for (int k4 = 0; k4 < 32; k4++) acc += dot4(w4[k4], xr4[kh * 32 + k4]);
        qs[kh * 512 + c] = acc;
    }
    __syncthreads();
    if (tid < 512) h1[tid] = fmaxf(qs[tid] + qs[512 + tid] + c1b[tid], 0.f);
    __syncthreads();

    // cls2, K-split-2: o = tid&511 (<396), 64 f4 each
    {
        const int kh = tid >> 9, o = tid & 511;
        if (o < NCL) {
            const f4* w4 = reinterpret_cast<const f4*>(c2w + (size_t)o * NF + kh * 256);
            float acc = 0.f;
            #pragma unroll 4
            for (int k4 = 0; k4 < 64; k4++) acc += dot4(w4[k4], h14[kh * 64 + k4]);
            qs[kh * 512 + o] = acc;
        }
    }
    __syncthreads();
    if (tid < NCL) out[(size_t)b * NCL + tid] = qs[tid] + qs[512 + tid] + c2b[tid];
}

// ---------------------------------------------------------------------------
extern "C" void kernel_launch(void* const* d_in, const int* in_sizes, int n_in,
                              void* d_out, int out_size, void* d_ws, size_t ws_size,
                              hipStream_t stream)
{
    const float* pred = (const float*)d_in[0];
    const float* hs   = (const float*)d_in[1];
    const float* f0   = (const float*)d_in[2];
    const float* f1   = (const float*)d_in[3];
    const float* f2   = (const float*)d_in[4];
    const float* f3   = (const float*)d_in[5];
    const float* ipw  = (const float*)d_in[6];
    const float* ipb  = (const float*)d_in[7];
    const float* inw  = (const float*)d_in[8];
    const float* inb  = (const float*)d_in[9];
    const float* ow   = (const float*)d_in[10];
    const float* ob   = (const float*)d_in[11];
    const float* l1w  = (const float*)d_in[12];
    const float* l1b  = (const float*)d_in[13];
    const float* l2w  = (const float*)d_in[14];
    const float* l2b  = (const float*)d_in[15];
    const float* ln1w = (const float*)d_in[16];
    const float* ln1b = (const float*)d_in[17];
    const float* ln2w = (const float*)d_in[18];
    const float* ln2b = (const float*)d_in[19];
    const float* c1w  = (const float*)d_in[20];
    const float* c1b  = (const float*)d_in[21];
    const float* c2w  = (const float*)d_in[22];
    const float* c2b  = (const float*)d_in[23];

    float* ws = (float*)d_ws;
    float* pooled = ws;                    // 65536
    float* tokG   = pooled + NB * 4 * ND;  // 98304
    float* biasW  = tokG + NB * 1536;      // 1024

    pool_cls_kernel<<<NB + 4 * NB * ND, 256, 0, stream>>>(
        pred, hs, f0, f1, f2, f3, pooled, tokG, biasW);
    xform_kernel<<<NB, 1024, 0, stream>>>(
        pooled, tokG, biasW, ipw, ipb, inw, inb, ow, ob, l1w, l1b, l2w, l2b,
        ln1w, ln1b, ln2w, ln2b, c1w, c1b, c2w, c2b, (float*)d_out);
}